// Round 1
// 275.587 us; speedup vs baseline: 1.1959x; 1.1959x over previous
//
#include <hip/hip_runtime.h>
#include <hip/hip_bf16.h>

// B,N,D,H = 4,2048,512,8 (DK=64). fp32 I/O; bf16 intermediates in ws.
// attn v4: 8-wave blocks (512 thr) at grid 256 -> 2 waves/SIMD (was 1).
// Heads-softmax is pointwise in (n,m), so the 32-m chunk is split across
// wave pairs: wave (ns, ms) computes QK+softmax for its 16-m half (all 8
// heads), P is pair-shared in LDS, PV runs full k=32 with each wave owning
// a disjoint d-tile pair -> aacc halves (64 regs), no cross-wave reduce.
#define B_  4
#define N_  2048
#define D_  512
#define H_  8

typedef unsigned short u16;
typedef __attribute__((ext_vector_type(8))) unsigned short ushort8;
typedef __attribute__((ext_vector_type(4))) unsigned short us4;
typedef __attribute__((ext_vector_type(8))) short short8;
typedef __attribute__((ext_vector_type(4))) float float4v;

__device__ __forceinline__ float bf2f(u16 u) {
    union { unsigned int i; float f; } v;
    v.i = ((unsigned int)u) << 16;
    return v.f;
}
__device__ __forceinline__ u16 f2bf(float f) {          // RNE
    union { float f; unsigned int i; } v;
    v.f = f;
    unsigned int r = v.i + 0x7FFFu + ((v.i >> 16) & 1u);
    return (u16)(r >> 16);
}
__device__ __forceinline__ u16 f2bf_fast(float f) {     // round-half-up
    union { float f; unsigned int i; } v;
    v.f = f;
    return (u16)((v.i + 0x8000u) >> 16);
}

// async global->LDS, 16B/lane, dest = wave-uniform base + lane*16 (m104 rule)
__device__ __forceinline__ void gload_lds16(const void* g, void* l) {
    __builtin_amdgcn_global_load_lds(
        (const __attribute__((address_space(1))) unsigned int*)g,
        (__attribute__((address_space(3))) unsigned int*)l, 16, 0, 0);
}

// ---------------------------------------------------------------------------
// wconv: Wq,Wo fp32 -> bf16, out = [Wqb | Wob]. grid (128, 2) x 256.
// ---------------------------------------------------------------------------
__global__ __launch_bounds__(256) void wconv(
    const float* __restrict__ Wq, const float* __restrict__ Wo,
    u16* __restrict__ out)
{
    const int idx = (blockIdx.x * 256 + threadIdx.x) * 8;
    const float* src = blockIdx.y ? Wo : Wq;
    u16* dst = out + (size_t)blockIdx.y * (D_ * D_) + idx;
    float4v a = *(const float4v*)(src + idx);
    float4v b = *(const float4v*)(src + idx + 4);
    ushort8 o;
    #pragma unroll
    for (int j = 0; j < 4; ++j) { o[j] = f2bf(a[j]); o[j + 4] = f2bf(b[j]); }
    *(ushort8*)dst = o;
}

// ---------------------------------------------------------------------------
// cvt3: Q,K,V fp32 -> bf16 slabs. grid (NBD/2048, 3) x 256.
// ---------------------------------------------------------------------------
__global__ __launch_bounds__(256) void cvt3(
    const float* __restrict__ Q, const float* __restrict__ K,
    const float* __restrict__ V, u16* __restrict__ out)
{
    const size_t NBD = (size_t)B_ * N_ * D_;
    const float* src = (blockIdx.y == 0) ? Q : ((blockIdx.y == 1) ? K : V);
    u16* dst = out + (size_t)blockIdx.y * NBD;
    size_t idx = ((size_t)blockIdx.x * 256 + threadIdx.x) * 8;
    float4v a = *(const float4v*)(src + idx);
    float4v b = *(const float4v*)(src + idx + 4);
    ushort8 o;
    #pragma unroll
    for (int j = 0; j < 4; ++j) { o[j] = f2bf(a[j]); o[j + 4] = f2bf(b[j]); }
    *(ushort8*)(dst + idx) = o;
}

// ---------------------------------------------------------------------------
// MFMA GEMM: C[M,512] = X @ W^T + bias.  1D grid, XCD swizzle: the 4 e-tiles
// of one (z,m) X-panel land on one XCD (flat&7 selects (z,m) low bits).
// INK: 0 = X fp32 (VALU cvt), 1 = X bf16 (gload), 2 = X0+X1 bf16 partials.
// WB16: W bf16 via gload. OUTB16: C bf16 (z==2 -> transposed Vpt[b][e][n]).
// 128x128 tile, 4 waves x 4x4 MFMA 16x16x32, BK=32.
// ---------------------------------------------------------------------------
template <int INK, bool WB16, bool OUTB16, int NZ>
__global__ __launch_bounds__(256) void proj_mfma(
    const void* __restrict__ X0v, const void* __restrict__ X1v,
    const void* __restrict__ X2v, const void* __restrict__ Wv,
    const float* __restrict__ bias, void* __restrict__ C0v, int M)
{
    __shared__ u16 As[128][32];
    __shared__ u16 Bs[128][32];

    const int t = threadIdx.x;
    // swizzle decode: flat = xcd + 8*(e + 4*g), zm = xcd + 8*g
    const int flat = blockIdx.x;
    const int xcd = flat & 7, rr = flat >> 3;
    const int eb = rr & 3, g = rr >> 2;
    const int zm = xcd + 8 * g;          // 0 .. 64*NZ-1
    const int z  = zm >> 6;
    const int e0 = eb * 128;
    const int m0 = (zm & 63) * 128;

    const void* Xv = (z == 0) ? X0v : ((z == 1) ? X1v : X2v);
    const int w = t >> 6, l = t & 63;
    const int lane16 = l & 15, quad = l >> 4;
    const int wr = (w >> 1) * 64;
    const int wc = (w & 1) * 64;

    float4v acc[4][4];
    #pragma unroll
    for (int i = 0; i < 4; ++i)
        #pragma unroll
        for (int j = 0; j < 4; ++j)
            acc[i][j] = (float4v){0.f, 0.f, 0.f, 0.f};

    for (int k0 = 0; k0 < 512; k0 += 32) {
        __syncthreads();

        // ---- stage A tile ----
        if (INK == 1) {
            const u16* X = (const u16*)Xv;
            #pragma unroll
            for (int i = 0; i < 2; ++i) {
                int r0 = w * 32 + i * 16;
                gload_lds16(X + (size_t)(m0 + r0 + (l >> 2)) * 512 + k0 + (l & 3) * 8,
                            &As[r0][0]);
            }
        } else if (INK == 0) {
            const float* X = (const float*)Xv;
            #pragma unroll
            for (int i = 0; i < 2; ++i) {
                int v   = t + 256 * i;
                int row = v >> 2;
                int c8  = (v & 3) * 8;
                const float* xp = X + (size_t)(m0 + row) * 512 + k0 + c8;
                float4v x0 = *(const float4v*)xp;
                float4v x1 = *(const float4v*)(xp + 4);
                ushort8 o;
                #pragma unroll
                for (int j = 0; j < 4; ++j) {
                    o[j]     = f2bf_fast(x0[j]);
                    o[j + 4] = f2bf_fast(x1[j]);
                }
                *(ushort8*)&As[row][c8] = o;
            }
        } else {  // INK == 2: sum of two bf16 partials
            const u16* P0 = (const u16*)X0v;
            const u16* P1 = (const u16*)X1v;
            #pragma unroll
            for (int i = 0; i < 2; ++i) {
                int v   = t + 256 * i;
                int row = v >> 2;
                int c8  = (v & 3) * 8;
                size_t gi = (size_t)(m0 + row) * 512 + k0 + c8;
                ushort8 a = *(const ushort8*)(P0 + gi);
                ushort8 b = *(const ushort8*)(P1 + gi);
                ushort8 o;
                #pragma unroll
                for (int j = 0; j < 8; ++j) o[j] = f2bf(bf2f(a[j]) + bf2f(b[j]));
                *(ushort8*)&As[row][c8] = o;
            }
        }

        // ---- stage B tile (W, bf16 via gload) ----
        if (WB16) {
            const u16* Wb = (const u16*)Wv;
            #pragma unroll
            for (int i = 0; i < 2; ++i) {
                int r0 = w * 32 + i * 16;
                gload_lds16(Wb + (size_t)(e0 + r0 + (l >> 2)) * 512 + k0 + (l & 3) * 8,
                            &Bs[r0][0]);
            }
        } else {
            const float* W = (const float*)Wv;
            #pragma unroll
            for (int i = 0; i < 2; ++i) {
                int v   = t + 256 * i;
                int row = v >> 2;
                int c8  = (v & 3) * 8;
                const float* wp = W + (size_t)(e0 + row) * 512 + k0 + c8;
                float4v w0 = *(const float4v*)wp;
                float4v w1 = *(const float4v*)(wp + 4);
                ushort8 o;
                #pragma unroll
                for (int j = 0; j < 4; ++j) {
                    o[j]     = f2bf_fast(w0[j]);
                    o[j + 4] = f2bf_fast(w1[j]);
                }
                *(ushort8*)&Bs[row][c8] = o;
            }
        }
        __syncthreads();

        short8 af[4], bfr[4];
        #pragma unroll
        for (int i = 0; i < 4; ++i)
            af[i] = *(const short8*)&As[wr + i * 16 + lane16][quad * 8];
        #pragma unroll
        for (int j = 0; j < 4; ++j)
            bfr[j] = *(const short8*)&Bs[wc + j * 16 + lane16][quad * 8];
        #pragma unroll
        for (int i = 0; i < 4; ++i)
            #pragma unroll
            for (int j = 0; j < 4; ++j)
                acc[i][j] = __builtin_amdgcn_mfma_f32_16x16x32_bf16(
                    af[i], bfr[j], acc[i][j], 0, 0, 0);
    }

    float bj[4];
    #pragma unroll
    for (int j = 0; j < 4; ++j) bj[j] = bias[e0 + wc + j * 16 + lane16];

    if (OUTB16) {
        if (z == 2) {   // transposed store: Vpt[b][e][n]
            u16* C = (u16*)C0v + 2 * (size_t)M * D_;
            #pragma unroll
            for (int i = 0; i < 4; ++i) {
                int mrow = m0 + wr + i * 16 + quad * 4;
                int bb = mrow >> 11, nb = mrow & (N_ - 1);
                #pragma unroll
                for (int j = 0; j < 4; ++j) {
                    int e = e0 + wc + j * 16 + lane16;
                    us4 o;
                    #pragma unroll
                    for (int r = 0; r < 4; ++r) o[r] = f2bf(acc[i][j][r] + bj[j]);
                    *(us4*)(C + (size_t)(bb * D_ + e) * N_ + nb) = o;
                }
            }
        } else {
            u16* C = (u16*)C0v + (size_t)z * (size_t)M * D_;
            #pragma unroll
            for (int i = 0; i < 4; ++i)
                #pragma unroll
                for (int j = 0; j < 4; ++j) {
                    int e = e0 + wc + j * 16 + lane16;
                    #pragma unroll
                    for (int r = 0; r < 4; ++r) {
                        int mrow = m0 + wr + i * 16 + quad * 4 + r;
                        C[(size_t)mrow * D_ + e] = f2bf(acc[i][j][r] + bj[j]);
                    }
                }
        }
    } else {
        float* C = (float*)C0v;
        #pragma unroll
        for (int i = 0; i < 4; ++i)
            #pragma unroll
            for (int j = 0; j < 4; ++j) {
                int e = e0 + wc + j * 16 + lane16;
                #pragma unroll
                for (int r = 0; r < 4; ++r) {
                    int mrow = m0 + wr + i * 16 + quad * 4 + r;
                    C[(size_t)mrow * D_ + e] = acc[i][j][r] + bj[j];
                }
            }
    }
}

// ---------------------------------------------------------------------------
// attn v4: 512 threads = 8 waves = 2 waves/SIMD (occupancy fix vs v3's 1).
// Wave (ns, ms): ns in 0..3 owns a 16-row n-tile, ms in 0..1 splits each
// 32-m chunk. Per chunk (3 barriers):
//   [bar] stage K (gload, 4 rows/wave) + V (regular loads, padded rows)
//   [bar] QK: 8 heads x own 16-m half (16 MFMA) -> register heads-softmax
//         (legal per-half: softmax couples heads only, pointwise in (n,m))
//         -> write own half of pair-shared Ps[ns]
//   [bar] PV: full k=32 (16 MFMA), each wave owns d-tiles dt = ms*2+{0,1}
// aacc is 8x2 (64 regs, was 8x4) so 2 waves/SIMD fits the 256-reg budget;
// each wave stores its own d-columns -> no cross-wave reduction.
// SPLIT=2 m-halves -> bf16 partial A buffers. XCD pinning: flat&7 = (b,z).
// Qp,Kp: [b][n][d]. Vpt: [b][d][n]. grid = 8 * (N/64) = 256 blocks.
// ---------------------------------------------------------------------------
__global__ __launch_bounds__(512, 2) void attn_mfma4(
    const u16* __restrict__ Qp, const u16* __restrict__ Kp,
    const u16* __restrict__ Vpt, u16* __restrict__ A0)
{
    __shared__ u16 Ks[32][520];        // 33,280 B (pad: uniform-bank frag reads)
    __shared__ u16 Vs[512][40];        // 40,960 B
    __shared__ u16 Ps[4][8][16][40];   // 40,960 B pair-shared P per n-tile

    const int t = threadIdx.x;
    const int w = t >> 6, l = t & 63;
    const int lane16 = l & 15, quad = l >> 4;
    const int ns = w >> 1, ms = w & 1;

    const int flat = blockIdx.x;
    const int xcd  = flat & 7;
    const int b = xcd >> 1;            // (b, z) pinned to one XCD
    const int z = xcd & 1;
    const int n0 = (flat >> 3) * 64 + ns * 16;   // this wave-pair's 16 rows
    const int seg  = N_ / 2;
    const int mbeg = z * seg;
    u16* A = A0 + (size_t)z * ((size_t)B_ * N_ * D_);

    // Q fragments: 8 heads x k=64, A-operand layout, persistent (64 VGPRs)
    short8 qfrag[8][2];
    {
        const u16* qb = Qp + ((size_t)(b * N_ + n0 + lane16) * D_ + quad * 8);
        #pragma unroll
        for (int h = 0; h < 8; ++h)
            #pragma unroll
            for (int dc = 0; dc < 2; ++dc)
                qfrag[h][dc] = *(const short8*)(qb + h * 64 + dc * 32);
    }

    float4v aacc[8][2];                // 8 heads x 2 owned d-tiles (64 regs)
    #pragma unroll
    for (int h = 0; h < 8; ++h)
        #pragma unroll
        for (int dt = 0; dt < 2; ++dt)
            aacc[h][dt] = (float4v){0.f, 0.f, 0.f, 0.f};

    for (int mc = mbeg; mc < mbeg + seg; mc += 32) {
        __syncthreads();   // prev chunk's Ks/Vs/Ps reads complete

        // ---- stage K: 32 rows x 1KB via gload, 4 rows per wave ----
        #pragma unroll
        for (int i = 0; i < 4; ++i) {
            int row = w * 4 + i;
            gload_lds16(Kp + (size_t)(b * N_ + mc + row) * D_ + l * 8, &Ks[row][0]);
        }
        // ---- stage V: 512 d-rows x 32 m (padded rows -> regular loads) ----
        #pragma unroll
        for (int i = 0; i < 4; ++i) {
            int v = i * 512 + t;
            int d = v >> 2, part = v & 3;
            ushort8 x = *(const ushort8*)(Vpt + (size_t)(b * D_ + d) * N_ + mc + part * 8);
            *(ushort8*)&Vs[d][part * 8] = x;
        }
        __syncthreads();   // staging visible

        // ---- QK^T (8 heads, own 16-m half) + register heads-softmax ----
        {
            float4v sacc[8];
            #pragma unroll
            for (int h = 0; h < 8; ++h) sacc[h] = (float4v){0.f, 0.f, 0.f, 0.f};
            #pragma unroll
            for (int h = 0; h < 8; ++h)
                #pragma unroll
                for (int dc = 0; dc < 2; ++dc) {
                    short8 kf = *(const short8*)
                        &Ks[ms * 16 + lane16][h * 64 + dc * 32 + quad * 8];
                    sacc[h] = __builtin_amdgcn_mfma_f32_16x16x32_bf16(
                        qfrag[h][dc], kf, sacc[h], 0, 0, 0);
                }
            #pragma unroll
            for (int r = 0; r < 4; ++r) {
                float p[8]; float sum = 0.f;
                #pragma unroll
                for (int h = 0; h < 8; ++h) {
                    p[h] = __expf(sacc[h][r] * 0.125f);   // 1/sqrt(64)
                    sum += p[h];
                }
                float inv = 1.f / sum;
                #pragma unroll
                for (int h = 0; h < 8; ++h)
                    Ps[ns][h][quad * 4 + r][ms * 16 + lane16] = f2bf(p[h] * inv);
            }
        }
        __syncthreads();   // pair's P halves visible

        // ---- PV: full k=32, each wave owns d-tiles ms*2 + {0,1} ----
        #pragma unroll
        for (int h = 0; h < 8; ++h) {
            short8 pf = *(const short8*)&Ps[ns][h][lane16][quad * 8];
            #pragma unroll
            for (int dt = 0; dt < 2; ++dt) {
                short8 vf = *(const short8*)
                    &Vs[h * 64 + (ms * 2 + dt) * 16 + lane16][quad * 8];
                aacc[h][dt] = __builtin_amdgcn_mfma_f32_16x16x32_bf16(
                    pf, vf, aacc[h][dt], 0, 0, 0);
            }
        }
    }

    // ---- store partial A (bf16), own d-columns only ----
    #pragma unroll
    for (int h = 0; h < 8; ++h)
        #pragma unroll
        for (int dt = 0; dt < 2; ++dt)
            #pragma unroll
            for (int r = 0; r < 4; ++r) {
                const int n = n0 + quad * 4 + r;
                const int d = h * 64 + (ms * 2 + dt) * 16 + lane16;
                A[(size_t)(b * N_ + n) * D_ + d] = f2bf(aacc[h][dt][r]);
            }
}

// ---------------------------------------------------------------------------
extern "C" void kernel_launch(void* const* d_in, const int* in_sizes, int n_in,
                              void* d_out, int out_size, void* d_ws, size_t ws_size,
                              hipStream_t stream)
{
    const float* Q  = (const float*)d_in[0];
    const float* K  = (const float*)d_in[1];
    const float* V  = (const float*)d_in[2];
    const float* Wq = (const float*)d_in[3];
    const float* bq = (const float*)d_in[4];
    const float* Wo = (const float*)d_in[5];
    const float* bo = (const float*)d_in[6];
    float* out = (float*)d_out;
    u16*   ws  = (u16*)d_ws;

    const size_t NBD = (size_t)B_ * N_ * D_;   // 4,194,304
    const int M = B_ * N_;                     // 8192

    const size_t need6 = (6 * NBD + 2 * (size_t)D_ * D_) * sizeof(u16); // 51.4 MB

    if (ws_size >= need6) {
        // Path A: bf16-ify inputs once; proj1 all-gload. Slab reuse:
        // S0=Qb->Pa, S1=Kb->Pb, S2=Vb, S3=Qp, S4=Kp, S5=Vpt, then Wb.
        u16* S0 = ws;
        u16* S1 = ws + NBD;
        u16* S2 = ws + 2 * NBD;
        u16* S3 = ws + 3 * NBD;
        u16* Wb = ws + 6 * NBD;            // [Wqb | Wob]

        cvt3<<<dim3((unsigned)(NBD / 2048), 3), dim3(256), 0, stream>>>(Q, K, V, S0);
        wconv<<<dim3(128, 2), dim3(256), 0, stream>>>(Wq, Wo, Wb);

        proj_mfma<1, true, true, 3><<<dim3(768), dim3(256), 0, stream>>>(
            S0, S1, S2, Wb, bq, S3, M);    // -> Qp(S3), Kp(S4), Vpt(S5)

        attn_mfma4<<<dim3(256), dim3(512), 0, stream>>>(
            S3, S3 + NBD, S3 + 2 * NBD, S0);   // partials -> S0, S1

        proj_mfma<2, true, false, 1><<<dim3(256), dim3(256), 0, stream>>>(
            S0, S1, S1, Wb + (size_t)D_ * D_, bo, out, M);
    } else {
        // Path B (proven 43.0 MB): fp32-X staging in proj1.
        u16* Qp  = ws;
        u16* Kp  = ws + NBD;
        u16* Vpt = ws + 2 * NBD;
        u16* Pa  = ws + 3 * NBD;
        u16* Pb  = ws + 4 * NBD;
        u16* Wb  = ws + 5 * NBD;

        wconv<<<dim3(128, 2), dim3(256), 0, stream>>>(Wq, Wo, Wb);

        proj_mfma<0, true, true, 3><<<dim3(768), dim3(256), 0, stream>>>(
            Q, K, V, Wb, bq, Qp, M);

        attn_mfma4<<<dim3(256), dim3(512), 0, stream>>>(Qp, Kp, Vpt, Pa);

        proj_mfma<2, true, false, 1><<<dim3(256), dim3(256), 0, stream>>>(
            Pa, Pb, Pb, Wb + (size_t)D_ * D_, bo, out, M);
    }
}